// Round 3
// baseline (556.549 us; speedup 1.0000x reference)
//
#include <hip/hip_runtime.h>
#include <math.h>

#define BS   8
#define CLS  4
#define CCH  256
#define HH   128
#define WW   128
#define HWSZ (HH * WW)   // 16384
#define LL   19
#define TKK  256
#define MHH  64
#define MWW  64

// ---------------------------------------------------------------------------
// Transpose W2 and W3 (256x256 each) into workspace so k_prep's reduction
// loops read them coalesced. Only launched when ws_size permits.
// [64][65] LDS padding -> conflict-free column reads.
// ---------------------------------------------------------------------------
__global__ __launch_bounds__(256) void k_tr(
    const float* __restrict__ W2, const float* __restrict__ W3,
    float* __restrict__ W2T, float* __restrict__ W3T) {
  __shared__ float tile[64][65];
  const int blk = blockIdx.x;
  const int m   = blk >> 4;
  const int q   = blk & 15;
  const int tr  = (q >> 2) * 64;   // input row origin
  const int tc  = (q & 3) * 64;    // input col origin
  const float* src = (m == 0) ? W2 : W3;
  float*       dst = (m == 0) ? W2T : W3T;
  const int t  = threadIdx.x;
  const int c  = t & 63;
  const int r0 = t >> 6;
#pragma unroll
  for (int rp = 0; rp < 64; rp += 4)
    tile[rp + r0][c] = src[(size_t)(tr + rp + r0) * TKK + tc + c];
  __syncthreads();
#pragma unroll
  for (int rp = 0; rp < 64; rp += 4)
    dst[(size_t)(tc + rp + r0) * TKK + tr + c] = tile[c][rp + r0];
}

// ---------------------------------------------------------------------------
// Prep (transposed-weight path): all three reductions are coalesced loads
// with an LDS-broadcast operand.
//   tq[t]       = sum_k tok[k] * W2T[k,t]
//   t3t[b,o,l]  = sum_k tok[k] * W3T[k,o] + b3[o]   (row pad 20)
//   u[b,l,c]    = (1/64) * sum_t W1[t,c] * tq[t]
// 1/64 folds the cls-mean (1/4) and softmax scale (1/sqrt(256)=1/16).
// ---------------------------------------------------------------------------
__global__ __launch_bounds__(256) void k_prep_tr(
    const float* __restrict__ token, const float* __restrict__ W1,
    const float* __restrict__ W2T, const float* __restrict__ W3T,
    const float* __restrict__ b3, float* __restrict__ u,
    float* __restrict__ t3t) {
  __shared__ float tok_s[TKK];
  __shared__ float tq_s[TKK];
  const int bl = blockIdx.x;           // b*LL + l
  const int b  = bl / LL;
  const int l  = bl - b * LL;
  const int t  = threadIdx.x;
  tok_s[t] = token[(size_t)bl * TKK + t];
  __syncthreads();
  float a2a = 0.f, a2b = 0.f, a3a = 0.f, a3b = 0.f;
#pragma unroll 8
  for (int k = 0; k < TKK; k += 2) {
    const float w2a = W2T[(size_t)(k + 0) * TKK + t];
    const float w2b = W2T[(size_t)(k + 1) * TKK + t];
    const float w3a = W3T[(size_t)(k + 0) * TKK + t];
    const float w3b = W3T[(size_t)(k + 1) * TKK + t];
    a2a += w2a * tok_s[k + 0];
    a2b += w2b * tok_s[k + 1];
    a3a += w3a * tok_s[k + 0];
    a3b += w3b * tok_s[k + 1];
  }
  tq_s[t] = a2a + a2b;
  t3t[((size_t)b * CCH + t) * 20 + l] = a3a + a3b + b3[t];
  __syncthreads();
  float s0 = 0.f, s1 = 0.f, s2 = 0.f, s3 = 0.f;
#pragma unroll 8
  for (int k = 0; k < TKK; k += 4) {
    s0 += W1[(size_t)(k + 0) * CCH + t] * tq_s[k + 0];
    s1 += W1[(size_t)(k + 1) * CCH + t] * tq_s[k + 1];
    s2 += W1[(size_t)(k + 2) * CCH + t] * tq_s[k + 2];
    s3 += W1[(size_t)(k + 3) * CCH + t] * tq_s[k + 3];
  }
  u[(size_t)bl * CCH + t] = (s0 + s1 + s2 + s3) * (1.0f / 64.0f);
}

// ---------------------------------------------------------------------------
// Prep (legacy path, round-0 verified): per-thread W2/W3 row gathers.
// Used when ws_size can't hold the transposed weights.
// ---------------------------------------------------------------------------
__global__ __launch_bounds__(256) void k_prep_leg(
    const float* __restrict__ token, const float* __restrict__ W1,
    const float* __restrict__ W2, const float* __restrict__ W3,
    const float* __restrict__ b3, float* __restrict__ u,
    float* __restrict__ t3t) {
  __shared__ float tok_s[TKK];
  __shared__ float tq_s[TKK];
  const int bl = blockIdx.x;           // b*LL + l
  const int b  = bl / LL;
  const int l  = bl - b * LL;
  const int t  = threadIdx.x;
  tok_s[t] = token[(size_t)bl * TKK + t];
  __syncthreads();
  const float4* w2r = (const float4*)(W2 + (size_t)t * TKK);
  const float4* w3r = (const float4*)(W3 + (size_t)t * TKK);
  float a2 = 0.f, a3 = 0.f;
#pragma unroll 8
  for (int i = 0; i < TKK / 4; ++i) {
    float4 x = w2r[i];
    float4 y = w3r[i];
    const float* ts = &tok_s[4 * i];
    a2 += x.x * ts[0] + x.y * ts[1] + x.z * ts[2] + x.w * ts[3];
    a3 += y.x * ts[0] + y.y * ts[1] + y.z * ts[2] + y.w * ts[3];
  }
  tq_s[t] = a2;
  t3t[((size_t)b * CCH + t) * 20 + l] = a3 + b3[t];
  __syncthreads();
  float s0 = 0.f, s1 = 0.f, s2 = 0.f, s3 = 0.f;
#pragma unroll 4
  for (int k = 0; k < TKK; k += 4) {
    s0 += W1[(k + 0) * CCH + t] * tq_s[k + 0];
    s1 += W1[(k + 1) * CCH + t] * tq_s[k + 1];
    s2 += W1[(k + 2) * CCH + t] * tq_s[k + 2];
    s3 += W1[(k + 3) * CCH + t] * tq_s[k + 3];
  }
  u[(size_t)bl * CCH + t] = (s0 + s1 + s2 + s3) * (1.0f / 64.0f);
}

// ---------------------------------------------------------------------------
// Main fused kernel, v5. Grid = 1024 blocks = (b, 128-px image row), b fastest.
// 512 threads = 8 waves; wave wv owns channels [wv*32, wv*32+32); lane owns
// pixel pair (float2) -> 512 B/wave per load instr.
// Occupancy model (m69 steps: waves/CU halves at VGPR 64/128/256): v2's 48-VGPR
// kernel was GRID-capped at 16 waves/CU (40% meas, HBM 2.7 TB/s, VALU 17% =
// latency-bound); 65..128 VGPR is the SAME 16-wave bucket (v3 proved it).
// Only VGPR<=64 + 8-wave blocks reaches 32 waves/CU -> __launch_bounds__(512,8)
// forces the <=64 budget. v2's near-identical inner loop compiled to 48 VGPR
// with MORE per-wave work, so this should fit without spills
// (falsifier: WRITE_SIZE > 131 MB or VGPR_Count > 64).
// Phase 4 reads t3 rows from LDS (overlaid on dead u_s region) as broadcast
// ds_read_b128 instead of 19-deep dependent s_load chains; 4-deep residual
// batching (8-deep would push phase-4 live state past the 64-reg budget).
// ---------------------------------------------------------------------------
__global__ __launch_bounds__(512, 8) void k_main(
    const float* __restrict__ mask, const float* __restrict__ fea,
    const float* __restrict__ u, const float* __restrict__ t3t,
    float* __restrict__ out) {
  // overlay: phase 1 = u_s[19][256] (4864 f), phase 4 = t3[256][20] (5120 f)
  __shared__ float4 sh_buf4[(CCH * 20) / 4];   // 20480 B, 16B aligned
  __shared__ float acc_s[LL][128];             // 9728 B
  float* sh_buf = (float*)sh_buf4;

  const int blk  = blockIdx.x;
  const int b    = blk & 7;          // b fastest: blocks sharing fea adjacent
  const int tile = blk >> 3;         // 0..127 = image row
  const int n0   = tile * WW;
  const int t    = threadIdx.x;
  const int lane = t & 63;
  const int wv   = t >> 6;           // 0..7

  // stage u (coalesced, rows contiguous) + zero the accumulator
  for (int k = t; k < LL * CCH; k += 512)
    sh_buf[k] = u[(size_t)b * LL * CCH + k];
  for (int k = t; k < LL * 128; k += 512) ((float*)acc_s)[k] = 0.f;

  // mask value shared by the lane's pixel pair: row tile/2, col lane
  const int hrow = tile >> 1;
  const size_t mbase = (((size_t)(b * CLS)) * MHH + hrow) * MWW + lane;
  const float m0 = mask[mbase + (size_t)0 * MHH * MWW];
  const float m1 = mask[mbase + (size_t)1 * MHH * MWW];
  const float m2 = mask[mbase + (size_t)2 * MHH * MWW];
  const float m3 = mask[mbase + (size_t)3 * MHH * MWW];

  __syncthreads();

  // fea batch indices: (4b+cl) % 8 == 4*(b&1) + cl
  const int f0 = (b & 1) * 4;
  const float* fb0 = fea + (size_t)(f0 + 0) * CCH * HWSZ + n0;
  const float* fb1 = fea + (size_t)(f0 + 1) * CCH * HWSZ + n0;
  const float* fb2 = fea + (size_t)(f0 + 2) * CCH * HWSZ + n0;
  const float* fb3 = fea + (size_t)(f0 + 3) * CCH * HWSZ + n0;

  float facc[LL][2];
#pragma unroll
  for (int l = 0; l < LL; ++l) { facc[l][0] = 0.f; facc[l][1] = 0.f; }

  const int c0 = wv * 32;
#pragma unroll 2
  for (int cc = 0; cc < 32; cc += 4) {
    float2 q[4];
#pragma unroll
    for (int j = 0; j < 4; ++j) {
      const size_t coff = (size_t)(c0 + cc + j) * HWSZ;
      const float2 v0 = ((const float2*)(fb0 + coff))[lane];
      const float2 v1 = ((const float2*)(fb1 + coff))[lane];
      const float2 v2 = ((const float2*)(fb2 + coff))[lane];
      const float2 v3 = ((const float2*)(fb3 + coff))[lane];
      q[j].x = v0.x * m0 + v1.x * m1 + v2.x * m2 + v3.x * m3;
      q[j].y = v0.y * m0 + v1.y * m1 + v2.y * m2 + v3.y * m3;
    }
#pragma unroll
    for (int l = 0; l < LL; ++l) {
      const float4 uu = *(const float4*)&sh_buf[l * CCH + c0 + cc];  // broadcast
      facc[l][0] += q[0].x * uu.x + q[1].x * uu.y + q[2].x * uu.z + q[3].x * uu.w;
      facc[l][1] += q[0].y * uu.x + q[1].y * uu.y + q[2].y * uu.z + q[3].y * uu.w;
    }
  }

  // cross-wave reduction: distinct addresses within a wave, 8-way across waves
#pragma unroll
  for (int l = 0; l < LL; ++l) {
    atomicAdd(&acc_s[l][2 * lane + 0], facc[l][0]);
    atomicAdd(&acc_s[l][2 * lane + 1], facc[l][1]);
  }
  __syncthreads();   // facc contributions in AND all u_s reads done

  // u_s region dead -> stage t3 slice for this b (5120 floats, coalesced)
  {
    const float* t3b = t3t + (size_t)b * CCH * 20;
    for (int k = t; k < CCH * 20; k += 512) sh_buf[k] = t3b[k];
  }
  // softmax over l, in-place (threads 0..127, one pixel each; stride-1 = free)
  if (t < 128) {
    float a[LL];
    float mx = -INFINITY;
#pragma unroll
    for (int l = 0; l < LL; ++l) { a[l] = acc_s[l][t]; mx = fmaxf(mx, a[l]); }
    float e[LL];
    float sum = 0.f;
#pragma unroll
    for (int l = 0; l < LL; ++l) { e[l] = __expf(a[l] - mx); sum += e[l]; }
    const float inv = 1.0f / sum;
#pragma unroll
    for (int l = 0; l < LL; ++l)
      acc_s[l][t] = (a[l] != 0.f) ? e[l] * inv : 0.f;  // replicate where(a!=0)
  }
  __syncthreads();

  // probs for this lane's pixel pair
  float2 p[LL];
#pragma unroll
  for (int l = 0; l < LL; ++l) p[l] = *(const float2*)&acc_s[l][2 * lane];

  // phase 4: wave-uniform o-slice (32 per wave); t3 rows broadcast from LDS
  const int wvu = __builtin_amdgcn_readfirstlane(wv);
  const int ob  = wvu * 32;
  for (int i0 = 0; i0 < 32; i0 += 4) {
    float2 r[4];   // 4 residual float2 loads in flight
#pragma unroll
    for (int j = 0; j < 4; ++j) {
      const size_t off = ((size_t)b * CCH + ob + i0 + j) * HWSZ + n0;
      r[j] = ((const float2*)(fea + off))[lane];
    }
#pragma unroll
    for (int j = 0; j < 4; ++j) {
      const int o = ob + i0 + j;
      const float4* tv = (const float4*)&sh_buf[o * 20];  // 80B rows, 16B aligned
      const float4 A = tv[0], B = tv[1], C = tv[2], D = tv[3], E = tv[4];
      const float sx =
          p[0].x  * A.x + p[1].x  * A.y + p[2].x  * A.z + p[3].x  * A.w +
          p[4].x  * B.x + p[5].x  * B.y + p[6].x  * B.z + p[7].x  * B.w +
          p[8].x  * C.x + p[9].x  * C.y + p[10].x * C.z + p[11].x * C.w +
          p[12].x * D.x + p[13].x * D.y + p[14].x * D.z + p[15].x * D.w +
          p[16].x * E.x + p[17].x * E.y + p[18].x * E.z;
      const float sy =
          p[0].y  * A.x + p[1].y  * A.y + p[2].y  * A.z + p[3].y  * A.w +
          p[4].y  * B.x + p[5].y  * B.y + p[6].y  * B.z + p[7].y  * B.w +
          p[8].y  * C.x + p[9].y  * C.y + p[10].y * C.z + p[11].y * C.w +
          p[12].y * D.x + p[13].y * D.y + p[14].y * D.z + p[15].y * D.w +
          p[16].y * E.x + p[17].y * E.y + p[18].y * E.z;
      const size_t off = ((size_t)b * CCH + o) * HWSZ + n0;
      float2 res;
      res.x = sx + r[j].x;
      res.y = sy + r[j].y;
      ((float2*)(out + off))[lane] = res;
    }
  }
}

// ---------------------------------------------------------------------------
extern "C" void kernel_launch(void* const* d_in, const int* in_sizes, int n_in,
                              void* d_out, int out_size, void* d_ws, size_t ws_size,
                              hipStream_t stream) {
  (void)in_sizes; (void)n_in; (void)out_size;
  const float* mask  = (const float*)d_in[0];
  const float* fea   = (const float*)d_in[1];
  const float* token = (const float*)d_in[2];
  const float* W1    = (const float*)d_in[3];
  const float* W2    = (const float*)d_in[4];
  const float* W3    = (const float*)d_in[5];
  const float* b3    = (const float*)d_in[6];
  float* out = (float*)d_out;

  float* u   = (float*)d_ws;                 // BS*LL*CCH floats   (38912)
  float* t3t = u + BS * LL * CCH;            // BS*CCH*20 floats   (40960)
  float* W2T = t3t + BS * CCH * 20;          // TKK*TKK floats     (65536)
  float* W3T = W2T + TKK * TKK;              // TKK*TKK floats     (65536)
  const size_t ws_need =
      (size_t)(BS * LL * CCH + BS * CCH * 20 + 2 * TKK * TKK) * sizeof(float);

  if (ws_size >= ws_need) {
    // coalesced-weight path (v4's OOB risk now guarded)
    k_tr<<<32, 256, 0, stream>>>(W2, W3, W2T, W3T);
    k_prep_tr<<<BS * LL, 256, 0, stream>>>(token, W1, W2T, W3T, b3, u, t3t);
  } else {
    // round-0 verified fallback: fits in 320 KB of workspace
    k_prep_leg<<<BS * LL, 256, 0, stream>>>(token, W1, W2, W3, b3, u, t3t);
  }
  k_main<<<(HWSZ / WW) * BS, 512, 0, stream>>>(mask, fea, u, t3t, out);
}

// Round 4
// 419.756 us; speedup vs baseline: 1.3259x; 1.3259x over previous
//
#include <hip/hip_runtime.h>
#include <math.h>

#define BS   8
#define CLS  4
#define CCH  256
#define HH   128
#define WW   128
#define HWSZ (HH * WW)   // 16384
#define LL   19
#define TKK  256
#define MHH  64
#define MWW  64

// ---------------------------------------------------------------------------
// Transpose W2 and W3 (256x256 each) into workspace so k_prep's reduction
// loops read them coalesced. Only launched when ws_size permits.
// [64][65] LDS padding -> conflict-free column reads.
// ---------------------------------------------------------------------------
__global__ __launch_bounds__(256) void k_tr(
    const float* __restrict__ W2, const float* __restrict__ W3,
    float* __restrict__ W2T, float* __restrict__ W3T) {
  __shared__ float tile[64][65];
  const int blk = blockIdx.x;
  const int m   = blk >> 4;
  const int q   = blk & 15;
  const int tr  = (q >> 2) * 64;   // input row origin
  const int tc  = (q & 3) * 64;    // input col origin
  const float* src = (m == 0) ? W2 : W3;
  float*       dst = (m == 0) ? W2T : W3T;
  const int t  = threadIdx.x;
  const int c  = t & 63;
  const int r0 = t >> 6;
#pragma unroll
  for (int rp = 0; rp < 64; rp += 4)
    tile[rp + r0][c] = src[(size_t)(tr + rp + r0) * TKK + tc + c];
  __syncthreads();
#pragma unroll
  for (int rp = 0; rp < 64; rp += 4)
    dst[(size_t)(tc + rp + r0) * TKK + tr + c] = tile[c][rp + r0];
}

// ---------------------------------------------------------------------------
// Prep (transposed-weight path): all three reductions are coalesced loads
// with an LDS-broadcast operand.
//   tq[t]       = sum_k tok[k] * W2T[k,t]
//   t3t[b,o,l]  = sum_k tok[k] * W3T[k,o] + b3[o]   (row pad 20)
//   u[b,l,c]    = (1/64) * sum_t W1[t,c] * tq[t]
// 1/64 folds the cls-mean (1/4) and softmax scale (1/sqrt(256)=1/16).
// ---------------------------------------------------------------------------
__global__ __launch_bounds__(256) void k_prep_tr(
    const float* __restrict__ token, const float* __restrict__ W1,
    const float* __restrict__ W2T, const float* __restrict__ W3T,
    const float* __restrict__ b3, float* __restrict__ u,
    float* __restrict__ t3t) {
  __shared__ float tok_s[TKK];
  __shared__ float tq_s[TKK];
  const int bl = blockIdx.x;           // b*LL + l
  const int b  = bl / LL;
  const int l  = bl - b * LL;
  const int t  = threadIdx.x;
  tok_s[t] = token[(size_t)bl * TKK + t];
  __syncthreads();
  float a2a = 0.f, a2b = 0.f, a3a = 0.f, a3b = 0.f;
#pragma unroll 8
  for (int k = 0; k < TKK; k += 2) {
    const float w2a = W2T[(size_t)(k + 0) * TKK + t];
    const float w2b = W2T[(size_t)(k + 1) * TKK + t];
    const float w3a = W3T[(size_t)(k + 0) * TKK + t];
    const float w3b = W3T[(size_t)(k + 1) * TKK + t];
    a2a += w2a * tok_s[k + 0];
    a2b += w2b * tok_s[k + 1];
    a3a += w3a * tok_s[k + 0];
    a3b += w3b * tok_s[k + 1];
  }
  tq_s[t] = a2a + a2b;
  t3t[((size_t)b * CCH + t) * 20 + l] = a3a + a3b + b3[t];
  __syncthreads();
  float s0 = 0.f, s1 = 0.f, s2 = 0.f, s3 = 0.f;
#pragma unroll 8
  for (int k = 0; k < TKK; k += 4) {
    s0 += W1[(size_t)(k + 0) * CCH + t] * tq_s[k + 0];
    s1 += W1[(size_t)(k + 1) * CCH + t] * tq_s[k + 1];
    s2 += W1[(size_t)(k + 2) * CCH + t] * tq_s[k + 2];
    s3 += W1[(size_t)(k + 3) * CCH + t] * tq_s[k + 3];
  }
  u[(size_t)bl * CCH + t] = (s0 + s1 + s2 + s3) * (1.0f / 64.0f);
}

// ---------------------------------------------------------------------------
// Prep (legacy path, round-0 verified): per-thread W2/W3 row gathers.
// Used when ws_size can't hold the transposed weights.
// ---------------------------------------------------------------------------
__global__ __launch_bounds__(256) void k_prep_leg(
    const float* __restrict__ token, const float* __restrict__ W1,
    const float* __restrict__ W2, const float* __restrict__ W3,
    const float* __restrict__ b3, float* __restrict__ u,
    float* __restrict__ t3t) {
  __shared__ float tok_s[TKK];
  __shared__ float tq_s[TKK];
  const int bl = blockIdx.x;           // b*LL + l
  const int b  = bl / LL;
  const int l  = bl - b * LL;
  const int t  = threadIdx.x;
  tok_s[t] = token[(size_t)bl * TKK + t];
  __syncthreads();
  const float4* w2r = (const float4*)(W2 + (size_t)t * TKK);
  const float4* w3r = (const float4*)(W3 + (size_t)t * TKK);
  float a2 = 0.f, a3 = 0.f;
#pragma unroll 8
  for (int i = 0; i < TKK / 4; ++i) {
    float4 x = w2r[i];
    float4 y = w3r[i];
    const float* ts = &tok_s[4 * i];
    a2 += x.x * ts[0] + x.y * ts[1] + x.z * ts[2] + x.w * ts[3];
    a3 += y.x * ts[0] + y.y * ts[1] + y.z * ts[2] + y.w * ts[3];
  }
  tq_s[t] = a2;
  t3t[((size_t)b * CCH + t) * 20 + l] = a3 + b3[t];
  __syncthreads();
  float s0 = 0.f, s1 = 0.f, s2 = 0.f, s3 = 0.f;
#pragma unroll 4
  for (int k = 0; k < TKK; k += 4) {
    s0 += W1[(k + 0) * CCH + t] * tq_s[k + 0];
    s1 += W1[(k + 1) * CCH + t] * tq_s[k + 1];
    s2 += W1[(k + 2) * CCH + t] * tq_s[k + 2];
    s3 += W1[(k + 3) * CCH + t] * tq_s[k + 3];
  }
  u[(size_t)bl * CCH + t] = (s0 + s1 + s2 + s3) * (1.0f / 64.0f);
}

// ---------------------------------------------------------------------------
// Main fused kernel, v6 = v5 with the launch-bounds calibration fixed.
// Grid = 1024 blocks = (b, 128-px image row), b fastest. 512 thr = 8 waves;
// wave wv owns channels [wv*32, wv*32+32); lane owns pixel pair (float2).
//
// Empirical VGPR-cap law on this toolchain: cap = 256/arg —
//   (256,4)->64 [round-0], (512,8)->32 [v5, spilled: WRITE 505 MB], (256,3)->85
//   [v3 compiled 76]. v5's arg=8 forced 32 regs < facc[19][2]=38 -> scratch.
// (512,4): cap 64 = the 8-waves/SIMD occupancy bucket (m69: VGPR<=64 ->
// 32 waves/CU). v2's identical inner loop compiled to 48 VGPR, so it fits.
// Grid 1024 = exactly 4 blocks/CU x 8 waves = 32 waves/CU = 100% cap
// (LDS 30.2 KB allows 5). Falsifier: VGPR>64 or WRITE_SIZE>140 MB = spills.
// Phase 4: t3 rows broadcast from LDS (overlay on dead u_s); 4-deep residual
// batching keeps phase-4 live state inside the 64-reg budget.
// ---------------------------------------------------------------------------
__global__ __launch_bounds__(512, 4) void k_main(
    const float* __restrict__ mask, const float* __restrict__ fea,
    const float* __restrict__ u, const float* __restrict__ t3t,
    float* __restrict__ out) {
  // overlay: phase 1 = u_s[19][256] (4864 f), phase 4 = t3[256][20] (5120 f)
  __shared__ float4 sh_buf4[(CCH * 20) / 4];   // 20480 B, 16B aligned
  __shared__ float acc_s[LL][128];             // 9728 B
  float* sh_buf = (float*)sh_buf4;

  const int blk  = blockIdx.x;
  const int b    = blk & 7;          // b fastest: blocks sharing fea adjacent
  const int tile = blk >> 3;         // 0..127 = image row
  const int n0   = tile * WW;
  const int t    = threadIdx.x;
  const int lane = t & 63;
  const int wv   = t >> 6;           // 0..7

  // stage u (coalesced, rows contiguous) + zero the accumulator
  for (int k = t; k < LL * CCH; k += 512)
    sh_buf[k] = u[(size_t)b * LL * CCH + k];
  for (int k = t; k < LL * 128; k += 512) ((float*)acc_s)[k] = 0.f;

  // mask value shared by the lane's pixel pair: row tile/2, col lane
  const int hrow = tile >> 1;
  const size_t mbase = (((size_t)(b * CLS)) * MHH + hrow) * MWW + lane;
  const float m0 = mask[mbase + (size_t)0 * MHH * MWW];
  const float m1 = mask[mbase + (size_t)1 * MHH * MWW];
  const float m2 = mask[mbase + (size_t)2 * MHH * MWW];
  const float m3 = mask[mbase + (size_t)3 * MHH * MWW];

  __syncthreads();

  // fea batch indices: (4b+cl) % 8 == 4*(b&1) + cl
  const int f0 = (b & 1) * 4;
  const float* fb0 = fea + (size_t)(f0 + 0) * CCH * HWSZ + n0;
  const float* fb1 = fea + (size_t)(f0 + 1) * CCH * HWSZ + n0;
  const float* fb2 = fea + (size_t)(f0 + 2) * CCH * HWSZ + n0;
  const float* fb3 = fea + (size_t)(f0 + 3) * CCH * HWSZ + n0;

  float facc[LL][2];
#pragma unroll
  for (int l = 0; l < LL; ++l) { facc[l][0] = 0.f; facc[l][1] = 0.f; }

  const int c0 = wv * 32;
#pragma unroll 2
  for (int cc = 0; cc < 32; cc += 4) {
    float2 q[4];
#pragma unroll
    for (int j = 0; j < 4; ++j) {
      const size_t coff = (size_t)(c0 + cc + j) * HWSZ;
      const float2 v0 = ((const float2*)(fb0 + coff))[lane];
      const float2 v1 = ((const float2*)(fb1 + coff))[lane];
      const float2 v2 = ((const float2*)(fb2 + coff))[lane];
      const float2 v3 = ((const float2*)(fb3 + coff))[lane];
      q[j].x = v0.x * m0 + v1.x * m1 + v2.x * m2 + v3.x * m3;
      q[j].y = v0.y * m0 + v1.y * m1 + v2.y * m2 + v3.y * m3;
    }
#pragma unroll
    for (int l = 0; l < LL; ++l) {
      const float4 uu = *(const float4*)&sh_buf[l * CCH + c0 + cc];  // broadcast
      facc[l][0] += q[0].x * uu.x + q[1].x * uu.y + q[2].x * uu.z + q[3].x * uu.w;
      facc[l][1] += q[0].y * uu.x + q[1].y * uu.y + q[2].y * uu.z + q[3].y * uu.w;
    }
  }

  // cross-wave reduction: distinct addresses within a wave, 8-way across waves
#pragma unroll
  for (int l = 0; l < LL; ++l) {
    atomicAdd(&acc_s[l][2 * lane + 0], facc[l][0]);
    atomicAdd(&acc_s[l][2 * lane + 1], facc[l][1]);
  }
  __syncthreads();   // facc contributions in AND all u_s reads done

  // u_s region dead -> stage t3 slice for this b (5120 floats, coalesced)
  {
    const float* t3b = t3t + (size_t)b * CCH * 20;
    for (int k = t; k < CCH * 20; k += 512) sh_buf[k] = t3b[k];
  }
  // softmax over l, in-place (threads 0..127, one pixel each; stride-1 = free)
  if (t < 128) {
    float a[LL];
    float mx = -INFINITY;
#pragma unroll
    for (int l = 0; l < LL; ++l) { a[l] = acc_s[l][t]; mx = fmaxf(mx, a[l]); }
    float e[LL];
    float sum = 0.f;
#pragma unroll
    for (int l = 0; l < LL; ++l) { e[l] = __expf(a[l] - mx); sum += e[l]; }
    const float inv = 1.0f / sum;
#pragma unroll
    for (int l = 0; l < LL; ++l)
      acc_s[l][t] = (a[l] != 0.f) ? e[l] * inv : 0.f;  // replicate where(a!=0)
  }
  __syncthreads();

  // probs for this lane's pixel pair
  float2 p[LL];
#pragma unroll
  for (int l = 0; l < LL; ++l) p[l] = *(const float2*)&acc_s[l][2 * lane];

  // phase 4: wave-uniform o-slice (32 per wave); t3 rows broadcast from LDS
  const int wvu = __builtin_amdgcn_readfirstlane(wv);
  const int ob  = wvu * 32;
  for (int i0 = 0; i0 < 32; i0 += 4) {
    float2 r[4];   // 4 residual float2 loads in flight
#pragma unroll
    for (int j = 0; j < 4; ++j) {
      const size_t off = ((size_t)b * CCH + ob + i0 + j) * HWSZ + n0;
      r[j] = ((const float2*)(fea + off))[lane];
    }
#pragma unroll
    for (int j = 0; j < 4; ++j) {
      const int o = ob + i0 + j;
      const float4* tv = (const float4*)&sh_buf[o * 20];  // 80B rows, 16B aligned
      const float4 A = tv[0], B = tv[1], C = tv[2], D = tv[3], E = tv[4];
      const float sx =
          p[0].x  * A.x + p[1].x  * A.y + p[2].x  * A.z + p[3].x  * A.w +
          p[4].x  * B.x + p[5].x  * B.y + p[6].x  * B.z + p[7].x  * B.w +
          p[8].x  * C.x + p[9].x  * C.y + p[10].x * C.z + p[11].x * C.w +
          p[12].x * D.x + p[13].x * D.y + p[14].x * D.z + p[15].x * D.w +
          p[16].x * E.x + p[17].x * E.y + p[18].x * E.z;
      const float sy =
          p[0].y  * A.x + p[1].y  * A.y + p[2].y  * A.z + p[3].y  * A.w +
          p[4].y  * B.x + p[5].y  * B.y + p[6].y  * B.z + p[7].y  * B.w +
          p[8].y  * C.x + p[9].y  * C.y + p[10].y * C.z + p[11].y * C.w +
          p[12].y * D.x + p[13].y * D.y + p[14].y * D.z + p[15].y * D.w +
          p[16].y * E.x + p[17].y * E.y + p[18].y * E.z;
      const size_t off = ((size_t)b * CCH + o) * HWSZ + n0;
      float2 res;
      res.x = sx + r[j].x;
      res.y = sy + r[j].y;
      ((float2*)(out + off))[lane] = res;
    }
  }
}

// ---------------------------------------------------------------------------
extern "C" void kernel_launch(void* const* d_in, const int* in_sizes, int n_in,
                              void* d_out, int out_size, void* d_ws, size_t ws_size,
                              hipStream_t stream) {
  (void)in_sizes; (void)n_in; (void)out_size;
  const float* mask  = (const float*)d_in[0];
  const float* fea   = (const float*)d_in[1];
  const float* token = (const float*)d_in[2];
  const float* W1    = (const float*)d_in[3];
  const float* W2    = (const float*)d_in[4];
  const float* W3    = (const float*)d_in[5];
  const float* b3    = (const float*)d_in[6];
  float* out = (float*)d_out;

  float* u   = (float*)d_ws;                 // BS*LL*CCH floats   (38912)
  float* t3t = u + BS * LL * CCH;            // BS*CCH*20 floats   (40960)
  float* W2T = t3t + BS * CCH * 20;          // TKK*TKK floats     (65536)
  float* W3T = W2T + TKK * TKK;              // TKK*TKK floats     (65536)
  const size_t ws_need =
      (size_t)(BS * LL * CCH + BS * CCH * 20 + 2 * TKK * TKK) * sizeof(float);

  if (ws_size >= ws_need) {
    // coalesced-weight path (guarded against small workspaces)
    k_tr<<<32, 256, 0, stream>>>(W2, W3, W2T, W3T);
    k_prep_tr<<<BS * LL, 256, 0, stream>>>(token, W1, W2T, W3T, b3, u, t3t);
  } else {
    // round-0 verified fallback: fits in 320 KB of workspace
    k_prep_leg<<<BS * LL, 256, 0, stream>>>(token, W1, W2, W3, b3, u, t3t);
  }
  k_main<<<(HWSZ / WW) * BS, 512, 0, stream>>>(mask, fea, u, t3t, out);
}

// Round 5
// 354.607 us; speedup vs baseline: 1.5695x; 1.1837x over previous
//
#include <hip/hip_runtime.h>
#include <math.h>

#define BS   8
#define CLS  4
#define CCH  256
#define HH   128
#define WW   128
#define HWSZ (HH * WW)   // 16384
#define LL   19
#define TKK  256
#define MHH  64
#define MWW  64

// ---------------------------------------------------------------------------
// Transpose W2 and W3 (256x256 each) into workspace so k_prep's reduction
// loops read them coalesced. Only launched when ws_size permits.
// [64][65] LDS padding -> conflict-free column reads.
// ---------------------------------------------------------------------------
__global__ __launch_bounds__(256) void k_tr(
    const float* __restrict__ W2, const float* __restrict__ W3,
    float* __restrict__ W2T, float* __restrict__ W3T) {
  __shared__ float tile[64][65];
  const int blk = blockIdx.x;
  const int m   = blk >> 4;
  const int q   = blk & 15;
  const int tr  = (q >> 2) * 64;   // input row origin
  const int tc  = (q & 3) * 64;    // input col origin
  const float* src = (m == 0) ? W2 : W3;
  float*       dst = (m == 0) ? W2T : W3T;
  const int t  = threadIdx.x;
  const int c  = t & 63;
  const int r0 = t >> 6;
#pragma unroll
  for (int rp = 0; rp < 64; rp += 4)
    tile[rp + r0][c] = src[(size_t)(tr + rp + r0) * TKK + tc + c];
  __syncthreads();
#pragma unroll
  for (int rp = 0; rp < 64; rp += 4)
    dst[(size_t)(tc + rp + r0) * TKK + tr + c] = tile[c][rp + r0];
}

// ---------------------------------------------------------------------------
// Prep (transposed-weight path): all three reductions are coalesced loads
// with an LDS-broadcast operand.
//   tq[t]       = sum_k tok[k] * W2T[k,t]
//   t3t[b,o,l]  = sum_k tok[k] * W3T[k,o] + b3[o]   (row pad 20)
//   u[b,l,c]    = (1/64) * sum_t W1[t,c] * tq[t]
// 1/64 folds the cls-mean (1/4) and softmax scale (1/sqrt(256)=1/16).
// ---------------------------------------------------------------------------
__global__ __launch_bounds__(256) void k_prep_tr(
    const float* __restrict__ token, const float* __restrict__ W1,
    const float* __restrict__ W2T, const float* __restrict__ W3T,
    const float* __restrict__ b3, float* __restrict__ u,
    float* __restrict__ t3t) {
  __shared__ float tok_s[TKK];
  __shared__ float tq_s[TKK];
  const int bl = blockIdx.x;           // b*LL + l
  const int b  = bl / LL;
  const int l  = bl - b * LL;
  const int t  = threadIdx.x;
  tok_s[t] = token[(size_t)bl * TKK + t];
  __syncthreads();
  float a2a = 0.f, a2b = 0.f, a3a = 0.f, a3b = 0.f;
#pragma unroll 8
  for (int k = 0; k < TKK; k += 2) {
    const float w2a = W2T[(size_t)(k + 0) * TKK + t];
    const float w2b = W2T[(size_t)(k + 1) * TKK + t];
    const float w3a = W3T[(size_t)(k + 0) * TKK + t];
    const float w3b = W3T[(size_t)(k + 1) * TKK + t];
    a2a += w2a * tok_s[k + 0];
    a2b += w2b * tok_s[k + 1];
    a3a += w3a * tok_s[k + 0];
    a3b += w3b * tok_s[k + 1];
  }
  tq_s[t] = a2a + a2b;
  t3t[((size_t)b * CCH + t) * 20 + l] = a3a + a3b + b3[t];
  __syncthreads();
  float s0 = 0.f, s1 = 0.f, s2 = 0.f, s3 = 0.f;
#pragma unroll 8
  for (int k = 0; k < TKK; k += 4) {
    s0 += W1[(size_t)(k + 0) * CCH + t] * tq_s[k + 0];
    s1 += W1[(size_t)(k + 1) * CCH + t] * tq_s[k + 1];
    s2 += W1[(size_t)(k + 2) * CCH + t] * tq_s[k + 2];
    s3 += W1[(size_t)(k + 3) * CCH + t] * tq_s[k + 3];
  }
  u[(size_t)bl * CCH + t] = (s0 + s1 + s2 + s3) * (1.0f / 64.0f);
}

// ---------------------------------------------------------------------------
// Prep (legacy path, round-0 verified): per-thread W2/W3 row gathers.
// Used when ws_size can't hold the transposed weights.
// ---------------------------------------------------------------------------
__global__ __launch_bounds__(256) void k_prep_leg(
    const float* __restrict__ token, const float* __restrict__ W1,
    const float* __restrict__ W2, const float* __restrict__ W3,
    const float* __restrict__ b3, float* __restrict__ u,
    float* __restrict__ t3t) {
  __shared__ float tok_s[TKK];
  __shared__ float tq_s[TKK];
  const int bl = blockIdx.x;           // b*LL + l
  const int b  = bl / LL;
  const int l  = bl - b * LL;
  const int t  = threadIdx.x;
  tok_s[t] = token[(size_t)bl * TKK + t];
  __syncthreads();
  const float4* w2r = (const float4*)(W2 + (size_t)t * TKK);
  const float4* w3r = (const float4*)(W3 + (size_t)t * TKK);
  float a2 = 0.f, a3 = 0.f;
#pragma unroll 8
  for (int i = 0; i < TKK / 4; ++i) {
    float4 x = w2r[i];
    float4 y = w3r[i];
    const float* ts = &tok_s[4 * i];
    a2 += x.x * ts[0] + x.y * ts[1] + x.z * ts[2] + x.w * ts[3];
    a3 += y.x * ts[0] + y.y * ts[1] + y.z * ts[2] + y.w * ts[3];
  }
  tq_s[t] = a2;
  t3t[((size_t)b * CCH + t) * 20 + l] = a3 + b3[t];
  __syncthreads();
  float s0 = 0.f, s1 = 0.f, s2 = 0.f, s3 = 0.f;
#pragma unroll 4
  for (int k = 0; k < TKK; k += 4) {
    s0 += W1[(k + 0) * CCH + t] * tq_s[k + 0];
    s1 += W1[(k + 1) * CCH + t] * tq_s[k + 1];
    s2 += W1[(k + 2) * CCH + t] * tq_s[k + 2];
    s3 += W1[(k + 3) * CCH + t] * tq_s[k + 3];
  }
  u[(size_t)bl * CCH + t] = (s0 + s1 + s2 + s3) * (1.0f / 64.0f);
}

// Load one 4-channel x 4-batch chunk (16 float2) into named buffer `buf`.
#define LOADC(buf, k)                                                        \
  {                                                                          \
    const size_t coff_ = (size_t)(c0 + (k) * 4) * HWSZ;                      \
    _Pragma("unroll")                                                        \
    for (int j = 0; j < 4; ++j) {                                            \
      const size_t co_ = coff_ + (size_t)j * HWSZ;                           \
      buf[j][0] = ((const float2*)(fb0 + co_))[lane];                        \
      buf[j][1] = ((const float2*)(fb1 + co_))[lane];                        \
      buf[j][2] = ((const float2*)(fb2 + co_))[lane];                        \
      buf[j][3] = ((const float2*)(fb3 + co_))[lane];                        \
    }                                                                        \
  }

// Consume chunk k from buffer `buf`: mask-combine -> 19 logit FMAs.
#define CONSC(buf, k)                                                        \
  {                                                                          \
    float2 q_[4];                                                            \
    _Pragma("unroll")                                                        \
    for (int j = 0; j < 4; ++j) {                                            \
      q_[j].x = buf[j][0].x * m0 + buf[j][1].x * m1 +                        \
                buf[j][2].x * m2 + buf[j][3].x * m3;                         \
      q_[j].y = buf[j][0].y * m0 + buf[j][1].y * m1 +                        \
                buf[j][2].y * m2 + buf[j][3].y * m3;                         \
    }                                                                        \
    _Pragma("unroll")                                                        \
    for (int l = 0; l < LL; ++l) {                                           \
      const float4 uu = *(const float4*)&u_s[l][c0 + (k) * 4];               \
      facc[l][0] += q_[0].x * uu.x + q_[1].x * uu.y +                        \
                    q_[2].x * uu.z + q_[3].x * uu.w;                         \
      facc[l][1] += q_[0].y * uu.x + q_[1].y * uu.y +                        \
                    q_[2].y * uu.z + q_[3].y * uu.w;                         \
    }                                                                        \
  }

// ---------------------------------------------------------------------------
// Main fused kernel, v7 = R0's proven 174-us structure (256 thr, 4 waves,
// wave owns 64 channels, lane owns pixel pair, grid 1024 b-fastest,
// s_load-based phase 4) with ONE change: phase 1 uses an explicit 2-chunk
// register double-buffer (chunk = 4 ch x 4 batches = 16 float2).
//
// Why: R0 compiled to 48 VGPR — too small to hold its declared 16-float2
// staging + facc[19][2] (38), i.e. the compiler collapsed staging to ~4
// loads in flight (~26 KB/CU at 13 waves; ~17 KB is breakeven for 6.3 TB/s
// at ~700 ns). Occupancy is GRID-capped at 16 waves/CU (4 blk/CU x 4 waves),
// so VGPRs up to 128 are free: spend them on in-flight loads. v5/v6 proved
// the 512-thread route regresses; this keeps the proven shape.
// (256,2) -> cap 128 (empirical law: cap = 256/arg; (256,4)->64 spilled in
// R2-prior, (512,8)->32 spilled v5). Live estimate ~120.
// Falsifier: WRITE_SIZE > 140 MB = spills -> revert to depth 1.
// ---------------------------------------------------------------------------
__global__ __launch_bounds__(256, 2) void k_main(
    const float* __restrict__ mask, const float* __restrict__ fea,
    const float* __restrict__ u, const float* __restrict__ t3t,
    float* __restrict__ out) {
  __shared__ float u_s[LL][CCH];     // [l][c]
  __shared__ float acc_s[LL][128];   // logits -> probs, [l][pix]

  const int blk  = blockIdx.x;
  const int b    = blk & 7;          // b fastest: blocks sharing fea adjacent
  const int tile = blk >> 3;         // 0..127 = image row
  const int n0   = tile * WW;
  const int t    = threadIdx.x;
  const int lane = t & 63;
  const int wv   = t >> 6;

  // stage u (coalesced) + zero the accumulator
#pragma unroll
  for (int l = 0; l < LL; ++l) u_s[l][t] = u[((size_t)b * LL + l) * CCH + t];
  for (int k = t; k < LL * 128; k += 256) ((float*)acc_s)[k] = 0.f;

  // mask value shared by the lane's pixel pair: row tile/2, col lane
  const int hrow = tile >> 1;
  const float m0 = mask[(((size_t)(b * CLS + 0)) * MHH + hrow) * MWW + lane];
  const float m1 = mask[(((size_t)(b * CLS + 1)) * MHH + hrow) * MWW + lane];
  const float m2 = mask[(((size_t)(b * CLS + 2)) * MHH + hrow) * MWW + lane];
  const float m3 = mask[(((size_t)(b * CLS + 3)) * MHH + hrow) * MWW + lane];

  __syncthreads();

  // fea batch indices: (4b+cl) % 8 == 4*(b&1) + cl
  const int f0 = (b & 1) * 4;
  const float* fb0 = fea + (size_t)(f0 + 0) * CCH * HWSZ + n0;
  const float* fb1 = fea + (size_t)(f0 + 1) * CCH * HWSZ + n0;
  const float* fb2 = fea + (size_t)(f0 + 2) * CCH * HWSZ + n0;
  const float* fb3 = fea + (size_t)(f0 + 3) * CCH * HWSZ + n0;

  float facc[LL][2];
#pragma unroll
  for (int l = 0; l < LL; ++l) { facc[l][0] = 0.f; facc[l][1] = 0.f; }

  const int c0 = wv * 64;

  // phase 1: 16 chunks of 4 channels, 2-deep register pipeline.
  // All indices compile-time (full unroll) -> registers, not scratch.
  {
    float2 A[4][4], B[4][4];   // [channel_j][batch]
    LOADC(A, 0);
#pragma unroll
    for (int k = 0; k < 16; k += 2) {
      LOADC(B, k + 1);         // issue next chunk before consuming current
      CONSC(A, k);
      if (k + 2 < 16) LOADC(A, k + 2);
      CONSC(B, k + 1);
    }
  }

  // cross-wave reduction: distinct addresses within a wave, 4-way across waves
#pragma unroll
  for (int l = 0; l < LL; ++l) {
    atomicAdd(&acc_s[l][2 * lane + 0], facc[l][0]);
    atomicAdd(&acc_s[l][2 * lane + 1], facc[l][1]);
  }
  __syncthreads();

  // softmax over l, in-place (threads 0..127, one pixel each; stride-1 = free)
  if (t < 128) {
    float a[LL];
    float mx = -INFINITY;
#pragma unroll
    for (int l = 0; l < LL; ++l) { a[l] = acc_s[l][t]; mx = fmaxf(mx, a[l]); }
    float e[LL];
    float sum = 0.f;
#pragma unroll
    for (int l = 0; l < LL; ++l) { e[l] = __expf(a[l] - mx); sum += e[l]; }
    const float inv = 1.0f / sum;
#pragma unroll
    for (int l = 0; l < LL; ++l)
      acc_s[l][t] = (a[l] != 0.f) ? e[l] * inv : 0.f;  // replicate where(a!=0)
  }
  __syncthreads();

  // probs for this lane's pixel pair
  float2 p[LL];
#pragma unroll
  for (int l = 0; l < LL; ++l) p[l] = *(const float2*)&acc_s[l][2 * lane];

  // phase 4: wave-uniform o-slice; t3 rows via scalar loads
  const int wvu = __builtin_amdgcn_readfirstlane(wv);
  const int ob  = wvu * 64;
#pragma unroll 4
  for (int i = 0; i < 64; ++i) {
    const int o = ob + i;
    const float* tr = t3t + ((size_t)b * CCH + o) * 20;  // uniform -> s_load
    float sx = 0.f, sy = 0.f;
#pragma unroll
    for (int l = 0; l < LL; ++l) {
      const float tv = tr[l];
      sx += p[l].x * tv;
      sy += p[l].y * tv;
    }
    const size_t off = ((size_t)b * CCH + o) * HWSZ + n0;
    const float2 r = ((const float2*)(fea + off))[lane];
    float2 res;
    res.x = sx + r.x;
    res.y = sy + r.y;
    ((float2*)(out + off))[lane] = res;
  }
}

// ---------------------------------------------------------------------------
extern "C" void kernel_launch(void* const* d_in, const int* in_sizes, int n_in,
                              void* d_out, int out_size, void* d_ws, size_t ws_size,
                              hipStream_t stream) {
  (void)in_sizes; (void)n_in; (void)out_size;
  const float* mask  = (const float*)d_in[0];
  const float* fea   = (const float*)d_in[1];
  const float* token = (const float*)d_in[2];
  const float* W1    = (const float*)d_in[3];
  const float* W2    = (const float*)d_in[4];
  const float* W3    = (const float*)d_in[5];
  const float* b3    = (const float*)d_in[6];
  float* out = (float*)d_out;

  float* u   = (float*)d_ws;                 // BS*LL*CCH floats   (38912)
  float* t3t = u + BS * LL * CCH;            // BS*CCH*20 floats   (40960)
  float* W2T = t3t + BS * CCH * 20;          // TKK*TKK floats     (65536)
  float* W3T = W2T + TKK * TKK;              // TKK*TKK floats     (65536)
  const size_t ws_need =
      (size_t)(BS * LL * CCH + BS * CCH * 20 + 2 * TKK * TKK) * sizeof(float);

  if (ws_size >= ws_need) {
    // coalesced-weight path (guarded against small workspaces)
    k_tr<<<32, 256, 0, stream>>>(W2, W3, W2T, W3T);
    k_prep_tr<<<BS * LL, 256, 0, stream>>>(token, W1, W2T, W3T, b3, u, t3t);
  } else {
    // round-0 verified fallback: fits in 320 KB of workspace
    k_prep_leg<<<BS * LL, 256, 0, stream>>>(token, W1, W2, W3, b3, u, t3t);
  }
  k_main<<<(HWSZ / WW) * BS, 256, 0, stream>>>(mask, fea, u, t3t, out);
}